// Round 6
// baseline (131.442 us; speedup 1.0000x reference)
//
#include <hip/hip_runtime.h>

// DIAGNOSTIC ROUND: the fused kernel has never appeared in the rocprof top-5
// (it hides under the five ~40us harness poison-fills), and 5 rounds of
// counter-blind structural edits moved the total by <1us. This build runs the
// IDENTICAL fused pipeline `reps` times (reps=2 at runtime, phases are
// idempotent -> bitwise-identical output, absmax 0.0). Doubling the kernel's
// duration lifts it above the fills so we finally get its VALUBusy /
// FETCH_SIZE / LDS-conflict / occupancy attribution. Next round's edit is
// pre-committed to the counter outcome (see session notes):
//   VALUBusy>=40% -> cut instructions; FETCH>=25MB -> table-reuse structure;
//   LDS conflicts big -> swizzle; all-low -> 2 blocks/CU + pipelining.
// Body is byte-identical to the round-5 kernel (verified absmax 0.0).

#define BATCH 512
#define FEAT  1024
#define NBITS (FEAT * 3)      // 3072
#define O1    2000
#define O2    1000
#define NCLS  10
#define G     2               // batch rows per block
#define NB    (BATCH / G)     // 256 blocks
#define NT    1024            // 16 waves

__global__ __launch_bounds__(NT, 4) void dwn_fused_diag(
    const float* __restrict__ x,       // [512,1024]
    const float* __restrict__ thr,     // [1024,3] == flat [3072]
    const float* __restrict__ luts1,   // [2000,64]
    const int*   __restrict__ idx1,    // [2000,6] in [0,3072)
    const float* __restrict__ luts2,   // [1000,64]
    const int*   __restrict__ idx2,    // [1000,6] in [0,2000)
    float* __restrict__ out,           // [512,10]
    int reps)                          // runtime -> pass 1 cannot be elided
{
    __shared__ unsigned s_bw[G][NBITS / 32];   // 768 B, bit-packed thermo
    __shared__ float s_h1[G][O1];              // 16 KB
    __shared__ float s_h2[G][O2];              // 8 KB
    __shared__ float s_part[G * NCLS * 10];    // 800 B

    const int t    = threadIdx.x;
    const int lane = t & 63;
    const int wl   = t >> 6;                   // wave in block, 0..15
    const int b0   = blockIdx.x * G;

    for (int rep = 0; rep < reps; ++rep) {
        __syncthreads();                       // isolate passes

        // ---- P1: thermometer encode -> bit-packed LDS via ballot ----
#pragma unroll
        for (int k = 0; k < 6; ++k) {
            const int task = k * 16 + wl;      // 0..95, exact
            const int r  = task & 1;
            const int g  = task >> 1;          // 0..47
            const int bi = (g << 6) | lane;
            const int f  = bi / 3;             // magic-mul
            const float xv = x[(b0 + r) * FEAT + f];
            const float tv = thr[bi];          // coalesced 256B/wave
            const unsigned long long m = __ballot(xv > tv);
            if (lane == 0) {
                s_bw[r][2 * g]     = (unsigned)m;
                s_bw[r][2 * g + 1] = (unsigned)(m >> 32);
            }
        }
        __syncthreads();

        // ---- P2: layer 1 — pure 6-bit table lookup ----
#pragma unroll
        for (int k = 0; k < 4; ++k) {
            const int i = t + k * NT;
            if (i < G * O1) {
                const int o = i >> 1;
                const int r = i & 1;
                const int2* ip = (const int2*)(idx1 + o * 6);
                const int2 p0 = ip[0], p1 = ip[1], p2 = ip[2];
                const int code =
                      ((int)((s_bw[r][p0.x >> 5] >> (p0.x & 31)) & 1u) << 5)
                    | ((int)((s_bw[r][p0.y >> 5] >> (p0.y & 31)) & 1u) << 4)
                    | ((int)((s_bw[r][p1.x >> 5] >> (p1.x & 31)) & 1u) << 3)
                    | ((int)((s_bw[r][p1.y >> 5] >> (p1.y & 31)) & 1u) << 2)
                    | ((int)((s_bw[r][p2.x >> 5] >> (p2.x & 31)) & 1u) << 1)
                    |  (int)((s_bw[r][p2.y >> 5] >> (p2.y & 31)) & 1u);
                s_h1[r][o] = luts1[o * 64 + code];
            }
        }
        __syncthreads();

        // ---- P3: layer 2 — 6-D multilinear interpolation, LSB-first fold ----
#pragma unroll
        for (int k = 0; k < 2; ++k) {
            const int i = t + k * NT;
            if (i < G * O2) {
                const int o = i >> 1;
                const int r = i & 1;
                const int2* ip = (const int2*)(idx2 + o * 6);
                const int2 p0 = ip[0], p1 = ip[1], p2 = ip[2];
                const float xv0 = s_h1[r][p0.x];
                const float xv1 = s_h1[r][p0.y];
                const float xv2 = s_h1[r][p1.x];
                const float xv3 = s_h1[r][p1.y];
                const float xv4 = s_h1[r][p2.x];
                const float xv5 = s_h1[r][p2.y];

                const float4* lp = (const float4*)(luts2 + (size_t)o * 64);
                float v[16];
#pragma unroll
                for (int q = 0; q < 16; ++q) { // fold x5 (bit0), x4 (bit1)
                    float4 e = lp[q];
                    float u0 = e.x + xv5 * (e.y - e.x);
                    float u1 = e.z + xv5 * (e.w - e.z);
                    v[q] = u0 + xv4 * (u1 - u0);
                }
#pragma unroll
                for (int q = 0; q < 8; ++q) v[q] = v[2*q] + xv3 * (v[2*q+1] - v[2*q]);
#pragma unroll
                for (int q = 0; q < 4; ++q) v[q] = v[2*q] + xv2 * (v[2*q+1] - v[2*q]);
#pragma unroll
                for (int q = 0; q < 2; ++q) v[q] = v[2*q] + xv1 * (v[2*q+1] - v[2*q]);
                s_h2[r][o] = v[0] + xv0 * (v[1] - v[0]);
            }
        }
        __syncthreads();

        // ---- P4: group sum / tau, exact 10x10 two-level order ----
        if (t < G * NCLS * 10) {               // 200 partial sums of 10
            int g = t / 10;
            int p = t % 10;
            int r   = g / NCLS;
            int cls = g % NCLS;
            const float* hp = &s_h2[r][cls * 100 + p * 10];
            float s = 0.0f;
#pragma unroll
            for (int j = 0; j < 10; ++j) s += hp[j];
            s_part[t] = s;
        }
        __syncthreads();
        if (t < G * NCLS) {                    // 20 final sums of 10 partials
            float s = 0.0f;
#pragma unroll
            for (int j = 0; j < 10; ++j) s += s_part[t * 10 + j];
            int r   = t / NCLS;
            int cls = t % NCLS;
            out[(b0 + r) * NCLS + cls] = s / 3.3333333f;
        }
    }
}

extern "C" void kernel_launch(void* const* d_in, const int* in_sizes, int n_in,
                              void* d_out, int out_size, void* d_ws, size_t ws_size,
                              hipStream_t stream) {
    const float* x     = (const float*)d_in[0];
    const float* thr   = (const float*)d_in[1];
    const float* luts1 = (const float*)d_in[2];
    const int*   idx1  = (const int*)  d_in[3];
    const float* luts2 = (const float*)d_in[4];
    const int*   idx2  = (const int*)  d_in[5];
    float* out = (float*)d_out;

    dwn_fused_diag<<<NB, NT, 0, stream>>>(x, thr, luts1, idx1, luts2, idx2,
                                          out, /*reps=*/2);
}